// Round 15
// baseline (329.032 us; speedup 1.0000x reference)
//
#include <hip/hip_runtime.h>

typedef _Float16 f16;
typedef _Float16 f16x8 __attribute__((ext_vector_type(8)));
typedef __fp16   fp16x2 __attribute__((ext_vector_type(2)));
typedef float    f32x16 __attribute__((ext_vector_type(16)));
typedef float    f32x4  __attribute__((ext_vector_type(4)));
typedef unsigned int u32;
typedef unsigned int u32x4 __attribute__((ext_vector_type(4)));

#define NPTS 262144

// ---- packed layout in d_ws (per net, net stride NET_F16 f16) ----
// Weight image = 70 contiguous 8KB chunks (512 x u32x4):
//   net0: L0 (1) | L1 (16) | L2 (16) | L3 (2) = 35 chunks; net1 same.
// Chunk contents: frag[mt][lane][8 f16] (L3: frag[kt][lane][8]).
// A-frag (mfma_f32_32x32x16_f16): A[m][k], m = 32*mt + (lane&31);
//   k(L0) = 8*hi + j canonical (zero-padded); k(L1/L2/L3) PERMUTED:
//   kphys(kt,hi,j) = 32*(kt>>1) + 16*(kt&1) + (j&3) + 8*(j>>2) + 4*hi
//   == C/D layout of previous layer's tile -> zero-shuffle epilogue.
// f32 biases at byte BIAS_BYTE, 800 floats/net, packed in C/D order.
#define NET_F16   143360
#define BIAS_BYTE 573440

static __device__ __forceinline__ u32 pkrtz(float a, float b) {
    fp16x2 h = __builtin_amdgcn_cvt_pkrtz(a, b);
    return __builtin_bit_cast(u32, h);
}
static __device__ __forceinline__ u32 relu_pk(float a, float b) {
    return pkrtz(fmaxf(a, 0.0f), fmaxf(b, 0.0f));
}

// ---------------- weight/bias packing kernel (unchanged, proven) ----------------
__global__ void prep_kernel(
    const float* __restrict__ dW0, const float* __restrict__ db0,
    const float* __restrict__ dW1, const float* __restrict__ db1,
    const float* __restrict__ dW2, const float* __restrict__ db2,
    const float* __restrict__ dW3, const float* __restrict__ db3,
    const float* __restrict__ sW0, const float* __restrict__ sb0,
    const float* __restrict__ sW1, const float* __restrict__ sb1,
    const float* __restrict__ sW2, const float* __restrict__ sb2,
    const float* __restrict__ sW3, const float* __restrict__ sb3,
    f16* __restrict__ wpk, float* __restrict__ bpk)
{
    const int ROWS = 17920;
    int t = blockIdx.x * 256 + threadIdx.x;
    if (t < 2 * ROWS) {
        int net = (t >= ROWS) ? 1 : 0;
        int r = t - net * ROWS;
        const float* W0 = net ? sW0 : dW0;
        const float* W1 = net ? sW1 : dW1;
        const float* W2 = net ? sW2 : dW2;
        const float* W3 = net ? sW3 : dW3;
        int K0 = net ? 8 : 3;
        f16* o = wpk + net * NET_F16;
        if (r < 512) {                                   // L0: canonical slots
            int lane = r & 63;
            int m  = 32 * (r >> 6) + (lane & 31);
            int kb = 8 * (lane >> 5);
            f16* q = o + r * 8;
            #pragma unroll
            for (int j = 0; j < 8; ++j) {
                int k = kb + j;
                q[j] = (f16)((k < K0) ? W0[k * 256 + m] : 0.0f);
            }
        } else if (r < 512 + 8192) {                     // L1: permuted k
            int rr = r - 512;
            int lane = rr & 63;
            int hh = lane >> 5;
            int m  = 32 * ((rr >> 6) & 7) + (lane & 31);
            int kt = rr >> 9;
            f16* q = o + 4096 + rr * 8;
            #pragma unroll
            for (int j = 0; j < 8; ++j) {
                int kp = 32 * (kt >> 1) + 16 * (kt & 1) + (j & 3) + 8 * (j >> 2) + 4 * hh;
                q[j] = (f16)W1[kp * 256 + m];
            }
        } else if (r < 512 + 16384) {                    // L2: permuted k
            int rr = r - (512 + 8192);
            int lane = rr & 63;
            int hh = lane >> 5;
            int m  = 32 * ((rr >> 6) & 7) + (lane & 31);
            int kt = rr >> 9;
            f16* q = o + 69632 + rr * 8;
            #pragma unroll
            for (int j = 0; j < 8; ++j) {
                int kp = 32 * (kt >> 1) + 16 * (kt & 1) + (j & 3) + 8 * (j >> 2) + 4 * hh;
                q[j] = (f16)W2[kp * 256 + m];
            }
        } else {                                         // L3: permuted k
            int rr = r - (512 + 16384);
            int lane = rr & 63;
            int hh = lane >> 5;
            int m  = lane & 31;
            int kt = rr >> 6;
            f16* q = o + 135168 + rr * 8;
            #pragma unroll
            for (int j = 0; j < 8; ++j) {
                int kp = 32 * (kt >> 1) + 16 * (kt & 1) + (j & 3) + 8 * (j >> 2) + 4 * hh;
                q[j] = (f16)((m < 3) ? W3[kp * 3 + m] : 0.0f);
            }
        }
    } else if (t < 2 * ROWS + 1600) {                    // biases (C/D order)
        int tb = t - 2 * ROWS;
        int net = (tb >= 800) ? 1 : 0;
        int i = tb - net * 800;
        float val;
        if (i < 768) {
            int layer = i >> 8;
            const float* bl = net ? (layer == 0 ? sb0 : layer == 1 ? sb1 : sb2)
                                  : (layer == 0 ? db0 : layer == 1 ? db1 : db2);
            int q  = i & 255;
            int rg = q & 15, h = (q >> 4) & 1;
            int m  = 32 * (q >> 5) + (rg & 3) + 8 * (rg >> 2) + 4 * h;
            val = bl[m];
        } else {
            int q  = i - 768;
            int rg = q & 15, h = q >> 4;
            int m  = (rg & 3) + 8 * (rg >> 2) + 4 * h;
            const float* b3 = net ? sb3 : db3;
            val = (m < 3) ? b3[m] : 0.0f;
        }
        bpk[net * 800 + i] = val;
    }
}

// One 256x256 chunk read DIRECTLY from global (L1/L2-cached), K-tile KT.
// 8 global_load_dwordx4 + 8 MFMA; compiler pipelines loads with staggered
// vmcnt within the 2-wave/SIMD register budget. No LDS, no sync.
#define CHUNK256_D(C, KT) do {                                                  \
    const u32x4* wq_ = ws + (C) * 512 + lane;                                   \
    const f16x8 xh_ = __builtin_bit_cast(f16x8, xf[KT]);                        \
    _Pragma("unroll")                                                           \
    for (int mt_ = 0; mt_ < 8; ++mt_) {                                         \
        const f16x8 a_ = __builtin_bit_cast(f16x8, wq_[mt_ * 64]);              \
        acc[mt_] = __builtin_amdgcn_mfma_f32_32x32x16_f16(a_, xh_, acc[mt_], 0, 0, 0); \
    }                                                                           \
} while (0)

#define BINIT(dst, boff) do {                                                   \
    const f32x4* b4_ = (const f32x4*)(biasl + (boff) + hi * 16);                \
    const f32x4 v0_ = b4_[0], v1_ = b4_[1], v2_ = b4_[2], v3_ = b4_[3];         \
    _Pragma("unroll")                                                           \
    for (int j = 0; j < 4; ++j) {                                               \
        (dst)[j] = v0_[j]; (dst)[4 + j] = v1_[j];                               \
        (dst)[8 + j] = v2_[j]; (dst)[12 + j] = v3_[j];                          \
    }                                                                           \
} while (0)

// Zero-shuffle epilogue (static indices only, rule #20).
#define EPI() do {                                                              \
    _Pragma("unroll")                                                           \
    for (int mt = 0; mt < 8; ++mt) {                                            \
        _Pragma("unroll")                                                       \
        for (int q = 0; q < 2; ++q) {                                           \
            u32x4 w;                                                            \
            w[0] = relu_pk(acc[mt][8*q+0], acc[mt][8*q+1]);                     \
            w[1] = relu_pk(acc[mt][8*q+2], acc[mt][8*q+3]);                     \
            w[2] = relu_pk(acc[mt][8*q+4], acc[mt][8*q+5]);                     \
            w[3] = relu_pk(acc[mt][8*q+6], acc[mt][8*q+7]);                     \
            xf[2*mt+q] = w;                                                     \
        }                                                                       \
    }                                                                           \
} while (0)

// ---------------- fused dual-MLP kernel ----------------
// 256 thr = 4 waves, 32 points/wave (pt=1), grid 2048, 2 blocks/CU ->
// 8 waves/CU. A-fragments read DIRECTLY from global: the 8KB/step window
// is L1-resident (shared by 8 waves), whole 573KB image is L2-resident.
// Zero staging, zero barriers, zero manual waitcnt: correctness by
// register dataflow only. LDS holds just the biases.
__launch_bounds__(256, 2)
__global__ void mlp_kernel(const float* __restrict__ gn, const float* __restrict__ gv,
                           const float* __restrict__ gro, const float* __restrict__ gr0,
                           const f16* __restrict__ wpk, const float* __restrict__ bpk,
                           float* __restrict__ out)
{
    __shared__ __align__(16) float biasl[1600];    // 6.4KB biases (only LDS)

    const int tid  = threadIdx.x;
    const int wv   = tid >> 6;
    const int lane = tid & 63;
    const int l32  = lane & 31;
    const int hi   = lane >> 5;
    const int p    = blockIdx.x * 128 + wv * 32 + l32;
    const u32x4* ws = (const u32x4*)wpk;           // 70-chunk contiguous stream

    // ---- biases -> LDS ----
    biasl[tid]        = bpk[tid];
    biasl[tid + 256]  = bpk[tid + 256];
    biasl[tid + 512]  = bpk[tid + 512];
    biasl[tid + 768]  = bpk[tid + 768];
    biasl[tid + 1024] = bpk[tid + 1024];
    biasl[tid + 1280] = bpk[tid + 1280];
    if (tid < 64) biasl[tid + 1536] = bpk[tid + 1536];

    // ---- inputs ----
    u32x4 xd = {0,0,0,0}, xs = {0,0,0,0};
    bool vis = false;
    if (hi == 0) {               // hi lanes hold k=8..15 (zero-padded)
        float nx = gn[3*p], ny = gn[3*p+1], nz = gn[3*p+2];
        float vx = gv[3*p], vy = gv[3*p+1], vz = gv[3*p+2];
        float ro = gro[p], rr = gr0[p];
        float ni = 1.0f / fmaxf(sqrtf(nx*nx + ny*ny + nz*nz), 1e-12f);
        float vi = 1.0f / fmaxf(sqrtf(vx*vx + vy*vy + vz*vz), 1e-12f);
        nx *= ni; ny *= ni; nz *= ni; vx *= vi; vy *= vi; vz *= vi;
        vis = (nx*vx + ny*vy + nz*vz) > 0.0f;
        xd[0] = pkrtz(nx, ny); xd[1] = pkrtz(nz, 0.0f);
        xs[0] = xd[0];         xs[1] = pkrtz(nz, vx);
        xs[2] = pkrtz(vy, vz); xs[3] = pkrtz(ro, rr);
    }

    __syncthreads();   // publish biasl (the kernel's only barrier)

    f32x16 acc[8];    // 128 regs -> AGPRs
    u32x4  xf[16];    // 64 VGPRs

    #pragma unroll
    for (int net = 0; net < 2; ++net) {
        const int cb = net * 35;
        const int bb = net * 800;
        const f16x8 xh0 = __builtin_bit_cast(f16x8, net ? xs : xd);

        // ---------- L0 (chunk cb+0) ----------
        {
            const u32x4* wq = ws + cb * 512 + lane;
            #pragma unroll
            for (int mt = 0; mt < 8; ++mt) {
                f32x16 ci;
                BINIT(ci, bb + mt * 32);
                const f16x8 a = __builtin_bit_cast(f16x8, wq[mt * 64]);
                acc[mt] = __builtin_amdgcn_mfma_f32_32x32x16_f16(a, xh0, ci, 0, 0, 0);
            }
        }
        EPI();

        // ---------- L1 (chunks cb+1 .. cb+16) ----------
        #pragma unroll
        for (int mt = 0; mt < 8; ++mt) BINIT(acc[mt], bb + 256 + mt * 32);
        #pragma unroll
        for (int kt = 0; kt < 16; ++kt) CHUNK256_D(cb + 1 + kt, kt);
        EPI();

        // ---------- L2 (chunks cb+17 .. cb+32) ----------
        #pragma unroll
        for (int mt = 0; mt < 8; ++mt) BINIT(acc[mt], bb + 512 + mt * 32);
        #pragma unroll
        for (int kt = 0; kt < 16; ++kt) CHUNK256_D(cb + 17 + kt, kt);
        EPI();

        // ---------- L3 (chunks cb+33, cb+34) ----------
        {
            f32x16 c3;
            BINIT(c3, bb + 768);
            const u32x4* bq0 = ws + (cb + 33) * 512 + lane;
            const u32x4* bq1 = ws + (cb + 34) * 512 + lane;
            #pragma unroll
            for (int i = 0; i < 8; ++i) {
                const f16x8 a = __builtin_bit_cast(f16x8, bq0[i * 64]);
                c3 = __builtin_amdgcn_mfma_f32_32x32x16_f16(a, __builtin_bit_cast(f16x8, xf[i]), c3, 0, 0, 0);
            }
            #pragma unroll
            for (int i = 0; i < 8; ++i) {
                const f16x8 a = __builtin_bit_cast(f16x8, bq1[i * 64]);
                c3 = __builtin_amdgcn_mfma_f32_32x32x16_f16(a, __builtin_bit_cast(f16x8, xf[8 + i]), c3, 0, 0, 0);
            }
            if (hi == 0) {
                float* op = out + net * (NPTS * 3) + p * 3;
                op[0] = vis ? c3[0] : 0.0f;
                op[1] = vis ? c3[1] : 0.0f;
                op[2] = vis ? c3[2] : 0.0f;
            }
        }
    }
}

extern "C" void kernel_launch(void* const* d_in, const int* in_sizes, int n_in,
                              void* d_out, int out_size, void* d_ws, size_t ws_size,
                              hipStream_t stream)
{
    f16*   wpk = (f16*)d_ws;
    float* bpk = (float*)((char*)d_ws + BIAS_BYTE);

    prep_kernel<<<147, 256, 0, stream>>>(
        (const float*)d_in[4],  (const float*)d_in[5],
        (const float*)d_in[6],  (const float*)d_in[7],
        (const float*)d_in[8],  (const float*)d_in[9],
        (const float*)d_in[10], (const float*)d_in[11],
        (const float*)d_in[12], (const float*)d_in[13],
        (const float*)d_in[14], (const float*)d_in[15],
        (const float*)d_in[16], (const float*)d_in[17],
        (const float*)d_in[18], (const float*)d_in[19],
        wpk, bpk);

    mlp_kernel<<<2048, 256, 0, stream>>>(
        (const float*)d_in[0], (const float*)d_in[1],
        (const float*)d_in[2], (const float*)d_in[3],
        wpk, bpk, (float*)d_out);
}

// Round 16
// 147.621 us; speedup vs baseline: 2.2289x; 2.2289x over previous
//
#include <hip/hip_runtime.h>

typedef _Float16 f16;
typedef _Float16 f16x8 __attribute__((ext_vector_type(8)));
typedef __fp16   fp16x2 __attribute__((ext_vector_type(2)));
typedef float    f32x16 __attribute__((ext_vector_type(16)));
typedef float    f32x4  __attribute__((ext_vector_type(4)));
typedef unsigned int u32;
typedef unsigned int u32x4 __attribute__((ext_vector_type(4)));

#define NPTS 262144

// ---- packed layout in d_ws (per net, net stride NET_F16 f16) ----
// Weight image = 70 contiguous 8KB chunks (512 x u32x4):
//   net0: L0 (1) | L1 (16) | L2 (16) | L3 (2) = 35 chunks; net1 same.
// Chunk contents: frag[mt][lane][8 f16] (L3: frag[kt][lane][8]).
// A-frag (mfma_f32_32x32x16_f16): A[m][k], m = 32*mt + (lane&31);
//   k(L0) = 8*hi + j canonical (zero-padded); k(L1/L2/L3) PERMUTED:
//   kphys(kt,hi,j) = 32*(kt>>1) + 16*(kt&1) + (j&3) + 8*(j>>2) + 4*hi
//   == C/D layout of previous layer's tile -> zero-shuffle epilogue.
// f32 biases at byte BIAS_BYTE, 800 floats/net, packed in C/D order.
#define NET_F16   143360
#define BIAS_BYTE 573440

static __device__ __forceinline__ u32 pkrtz(float a, float b) {
    fp16x2 h = __builtin_amdgcn_cvt_pkrtz(a, b);
    return __builtin_bit_cast(u32, h);
}
static __device__ __forceinline__ u32 relu_pk(float a, float b) {
    return pkrtz(fmaxf(a, 0.0f), fmaxf(b, 0.0f));
}

// ---------------- weight/bias packing kernel (unchanged, proven) ----------------
__global__ void prep_kernel(
    const float* __restrict__ dW0, const float* __restrict__ db0,
    const float* __restrict__ dW1, const float* __restrict__ db1,
    const float* __restrict__ dW2, const float* __restrict__ db2,
    const float* __restrict__ dW3, const float* __restrict__ db3,
    const float* __restrict__ sW0, const float* __restrict__ sb0,
    const float* __restrict__ sW1, const float* __restrict__ sb1,
    const float* __restrict__ sW2, const float* __restrict__ sb2,
    const float* __restrict__ sW3, const float* __restrict__ sb3,
    f16* __restrict__ wpk, float* __restrict__ bpk)
{
    const int ROWS = 17920;
    int t = blockIdx.x * 256 + threadIdx.x;
    if (t < 2 * ROWS) {
        int net = (t >= ROWS) ? 1 : 0;
        int r = t - net * ROWS;
        const float* W0 = net ? sW0 : dW0;
        const float* W1 = net ? sW1 : dW1;
        const float* W2 = net ? sW2 : dW2;
        const float* W3 = net ? sW3 : dW3;
        int K0 = net ? 8 : 3;
        f16* o = wpk + net * NET_F16;
        if (r < 512) {                                   // L0: canonical slots
            int lane = r & 63;
            int m  = 32 * (r >> 6) + (lane & 31);
            int kb = 8 * (lane >> 5);
            f16* q = o + r * 8;
            #pragma unroll
            for (int j = 0; j < 8; ++j) {
                int k = kb + j;
                q[j] = (f16)((k < K0) ? W0[k * 256 + m] : 0.0f);
            }
        } else if (r < 512 + 8192) {                     // L1: permuted k
            int rr = r - 512;
            int lane = rr & 63;
            int hh = lane >> 5;
            int m  = 32 * ((rr >> 6) & 7) + (lane & 31);
            int kt = rr >> 9;
            f16* q = o + 4096 + rr * 8;
            #pragma unroll
            for (int j = 0; j < 8; ++j) {
                int kp = 32 * (kt >> 1) + 16 * (kt & 1) + (j & 3) + 8 * (j >> 2) + 4 * hh;
                q[j] = (f16)W1[kp * 256 + m];
            }
        } else if (r < 512 + 16384) {                    // L2: permuted k
            int rr = r - (512 + 8192);
            int lane = rr & 63;
            int hh = lane >> 5;
            int m  = 32 * ((rr >> 6) & 7) + (lane & 31);
            int kt = rr >> 9;
            f16* q = o + 69632 + rr * 8;
            #pragma unroll
            for (int j = 0; j < 8; ++j) {
                int kp = 32 * (kt >> 1) + 16 * (kt & 1) + (j & 3) + 8 * (j >> 2) + 4 * hh;
                q[j] = (f16)W2[kp * 256 + m];
            }
        } else {                                         // L3: permuted k
            int rr = r - (512 + 16384);
            int lane = rr & 63;
            int hh = lane >> 5;
            int m  = lane & 31;
            int kt = rr >> 6;
            f16* q = o + 135168 + rr * 8;
            #pragma unroll
            for (int j = 0; j < 8; ++j) {
                int kp = 32 * (kt >> 1) + 16 * (kt & 1) + (j & 3) + 8 * (j >> 2) + 4 * hh;
                q[j] = (f16)((m < 3) ? W3[kp * 3 + m] : 0.0f);
            }
        }
    } else if (t < 2 * ROWS + 1600) {                    // biases (C/D order)
        int tb = t - 2 * ROWS;
        int net = (tb >= 800) ? 1 : 0;
        int i = tb - net * 800;
        float val;
        if (i < 768) {
            int layer = i >> 8;
            const float* bl = net ? (layer == 0 ? sb0 : layer == 1 ? sb1 : sb2)
                                  : (layer == 0 ? db0 : layer == 1 ? db1 : db2);
            int q  = i & 255;
            int rg = q & 15, h = (q >> 4) & 1;
            int m  = 32 * (q >> 5) + (rg & 3) + 8 * (rg >> 2) + 4 * h;
            val = bl[m];
        } else {
            int q  = i - 768;
            int rg = q & 15, h = q >> 4;
            int m  = (rg & 3) + 8 * (rg >> 2) + 4 * h;
            const float* b3 = net ? sb3 : db3;
            val = (m < 3) ? b3[m] : 0.0f;
        }
        bpk[net * 800 + i] = val;
    }
}

// Counted-wait + barrier (T3/T4, R12/R14-proven at 4-wave blocks).
#define WAITB(WS) do {                                                          \
    asm volatile("s_waitcnt vmcnt(" WS ") lgkmcnt(0)" ::: "memory");            \
    __builtin_amdgcn_sched_barrier(0);                                          \
    __builtin_amdgcn_s_barrier();                                               \
    __builtin_amdgcn_sched_barrier(0);                                          \
} while (0)

// Stage a 3-chunk batch (chunks C0..C0+2, C0 = 3b) into slot S = b%3.
// Wave wv moves rows woff..woff+127 of each chunk: 6 loads/wave/batch.
#define STAGE3(S, C0) do {                                                      \
    _Pragma("unroll")                                                           \
    for (int i_ = 0; i_ < 3; ++i_) {                                            \
        const u32x4* g_ = ws + ((C0) + i_) * 512 + woff + lane;                 \
        u32x4* l_ = &ring[S][i_ * 512 + woff];                                  \
        __builtin_amdgcn_global_load_lds(                                       \
            (const __attribute__((address_space(1))) void*)g_,                  \
            (__attribute__((address_space(3))) void*)l_, 16, 0, 0);             \
        __builtin_amdgcn_global_load_lds(                                       \
            (const __attribute__((address_space(1))) void*)(g_ + 64),           \
            (__attribute__((address_space(3))) void*)(l_ + 64), 16, 0, 0);      \
    }                                                                           \
} while (0)
// Last batch (23) = chunk 69 only -> slot 2, offset 0 (69/3=23, 23%3=2, 69%3=0).
#define STAGE_LAST() do {                                                       \
    const u32x4* g_ = ws + 69 * 512 + woff + lane;                              \
    u32x4* l_ = &ring[2][woff];                                                 \
    __builtin_amdgcn_global_load_lds(                                           \
        (const __attribute__((address_space(1))) void*)g_,                      \
        (__attribute__((address_space(3))) void*)l_, 16, 0, 0);                 \
    __builtin_amdgcn_global_load_lds(                                           \
        (const __attribute__((address_space(1))) void*)(g_ + 64),               \
        (__attribute__((address_space(3))) void*)(l_ + 64), 16, 0, 0);          \
} while (0)

// Chunk C consumed as 256x256 K-tile KT. slot = (C/3)%3, offset = (C%3)*512
// -- all compile-time (C literal). pt=1: 8 ds_read_b128 + 8 MFMA.
#define CHW(C, KT) do {                                                         \
    const u32x4* bq_ = &ring[((C) / 3) % 3][((C) % 3) * 512];                   \
    const f16x8 xh_ = __builtin_bit_cast(f16x8, xf[KT]);                        \
    _Pragma("unroll")                                                           \
    for (int mt_ = 0; mt_ < 8; ++mt_) {                                         \
        const f16x8 a_ = __builtin_bit_cast(f16x8, bq_[mt_ * 64 + lane]);       \
        acc[mt_] = __builtin_amdgcn_mfma_f32_32x32x16_f16(a_, xh_, acc[mt_], 0, 0, 0); \
    }                                                                           \
} while (0)

// L3 chunk C with xf base HB into c3.
#define L3W(C, HB) do {                                                         \
    const u32x4* bq_ = &ring[((C) / 3) % 3][((C) % 3) * 512];                   \
    _Pragma("unroll")                                                           \
    for (int i_ = 0; i_ < 8; ++i_) {                                            \
        const f16x8 a_ = __builtin_bit_cast(f16x8, bq_[i_ * 64 + lane]);        \
        c3 = __builtin_amdgcn_mfma_f32_32x32x16_f16(                            \
                a_, __builtin_bit_cast(f16x8, xf[(HB) + i_]), c3, 0, 0, 0);     \
    }                                                                           \
} while (0)

// L0 of net N from chunk C (bias-init per-mt, canonical input frag XH).
#define L0W(C, BB, XH) do {                                                     \
    const u32x4* bq_ = &ring[((C) / 3) % 3][((C) % 3) * 512];                   \
    _Pragma("unroll")                                                           \
    for (int mt_ = 0; mt_ < 8; ++mt_) {                                         \
        f32x16 ci_;                                                             \
        BINIT(ci_, (BB) + mt_ * 32);                                            \
        const f16x8 a_ = __builtin_bit_cast(f16x8, bq_[mt_ * 64 + lane]);       \
        acc[mt_] = __builtin_amdgcn_mfma_f32_32x32x16_f16(a_, XH, ci_, 0, 0, 0);\
    }                                                                           \
} while (0)

#define BINIT(dst, boff) do {                                                   \
    const f32x4* b4_ = (const f32x4*)(biasl + (boff) + hi * 16);                \
    const f32x4 v0_ = b4_[0], v1_ = b4_[1], v2_ = b4_[2], v3_ = b4_[3];         \
    _Pragma("unroll")                                                           \
    for (int j = 0; j < 4; ++j) {                                               \
        (dst)[j] = v0_[j]; (dst)[4 + j] = v1_[j];                               \
        (dst)[8 + j] = v2_[j]; (dst)[12 + j] = v3_[j];                          \
    }                                                                           \
} while (0)

#define BINIT_ALL(boff) do {                                                    \
    _Pragma("unroll")                                                           \
    for (int mt = 0; mt < 8; ++mt) BINIT(acc[mt], (boff) + mt * 32);            \
} while (0)

// Zero-shuffle epilogue (static indices only, rule #20).
#define EPI() do {                                                              \
    _Pragma("unroll")                                                           \
    for (int mt = 0; mt < 8; ++mt) {                                            \
        _Pragma("unroll")                                                       \
        for (int q = 0; q < 2; ++q) {                                           \
            u32x4 w;                                                            \
            w[0] = relu_pk(acc[mt][8*q+0], acc[mt][8*q+1]);                     \
            w[1] = relu_pk(acc[mt][8*q+2], acc[mt][8*q+3]);                     \
            w[2] = relu_pk(acc[mt][8*q+4], acc[mt][8*q+5]);                     \
            w[3] = relu_pk(acc[mt][8*q+6], acc[mt][8*q+7]);                     \
            xf[2*mt+q] = w;                                                     \
        }                                                                       \
    }                                                                           \
} while (0)

// ---------------- fused dual-MLP kernel ----------------
// 256 thr = 4 waves, 32 points/wave (pt=1), grid 2048, 2 blocks/CU,
// 2 waves/SIMD. 3-chunk batches in a 3-slot ring (72KB), depth-2
// counted-vmcnt: 24 barrier-steps for the whole 70-chunk stream (vs 36).
__launch_bounds__(256, 2)
__global__ void mlp_kernel(const float* __restrict__ gn, const float* __restrict__ gv,
                           const float* __restrict__ gro, const float* __restrict__ gr0,
                           const f16* __restrict__ wpk, const float* __restrict__ bpk,
                           float* __restrict__ out)
{
    __shared__ u32x4 ring[3][1536];                // 3 x 24KB slots = 72KB
    __shared__ __align__(16) float biasl[1600];    // 6.4KB biases

    const int tid  = threadIdx.x;
    const int wv   = tid >> 6;
    const int lane = tid & 63;
    const int l32  = lane & 31;
    const int hi   = lane >> 5;
    const int p    = blockIdx.x * 128 + wv * 32 + l32;
    const int woff = wv * 128;
    const u32x4* ws = (const u32x4*)wpk;           // 70-chunk contiguous stream

    // ---- biases -> LDS ----
    biasl[tid]        = bpk[tid];
    biasl[tid + 256]  = bpk[tid + 256];
    biasl[tid + 512]  = bpk[tid + 512];
    biasl[tid + 768]  = bpk[tid + 768];
    biasl[tid + 1024] = bpk[tid + 1024];
    biasl[tid + 1280] = bpk[tid + 1280];
    if (tid < 64) biasl[tid + 1536] = bpk[tid + 1536];

    // ---- inputs (before the pipeline: keeps the vmcnt window pure) ----
    u32x4 xd = {0,0,0,0}, xs = {0,0,0,0};
    bool vis = false;
    if (hi == 0) {               // hi lanes hold k=8..15 (zero-padded)
        float nx = gn[3*p], ny = gn[3*p+1], nz = gn[3*p+2];
        float vx = gv[3*p], vy = gv[3*p+1], vz = gv[3*p+2];
        float ro = gro[p], rr = gr0[p];
        float ni = 1.0f / fmaxf(sqrtf(nx*nx + ny*ny + nz*nz), 1e-12f);
        float vi = 1.0f / fmaxf(sqrtf(vx*vx + vy*vy + vz*vz), 1e-12f);
        nx *= ni; ny *= ni; nz *= ni; vx *= vi; vy *= vi; vz *= vi;
        vis = (nx*vx + ny*vy + nz*vz) > 0.0f;
        xd[0] = pkrtz(nx, ny); xd[1] = pkrtz(nz, 0.0f);
        xs[0] = xd[0];         xs[1] = pkrtz(nz, vx);
        xs[2] = pkrtz(vy, vz); xs[3] = pkrtz(ro, rr);
    }

    // drain input/bias traffic, publish biasl (single full sync, pre-pipeline)
    __syncthreads();

    // ---- prologue: batches 0 (chunks 0-2 -> slot 0) and 1 (3-5 -> slot 1) ----
    STAGE3(0, 0);
    STAGE3(1, 3);

    f32x16 acc[8];    // 128 regs -> AGPRs
    u32x4  xf[16];    // 64 VGPRs
    const f16x8 xh0 = __builtin_bit_cast(f16x8, xd);
    const f16x8 xh1 = __builtin_bit_cast(f16x8, xs);

    // ================= net0 =================
    // t0: L0 + L1 kt0,1
    WAITB("6"); STAGE3(2, 6);
    L0W(0, 0, xh0); EPI(); BINIT_ALL(256);
    CHW(1, 0); CHW(2, 1);
    // t1..t4: L1 kt2..13
    WAITB("6"); STAGE3(0, 9);  CHW(3, 2);  CHW(4, 3);  CHW(5, 4);
    WAITB("6"); STAGE3(1, 12); CHW(6, 5);  CHW(7, 6);  CHW(8, 7);
    WAITB("6"); STAGE3(2, 15); CHW(9, 8);  CHW(10, 9); CHW(11, 10);
    WAITB("6"); STAGE3(0, 18); CHW(12, 11); CHW(13, 12); CHW(14, 13);
    // t5: L1 kt14,15 | L2 kt0
    WAITB("6"); STAGE3(1, 21);
    CHW(15, 14); CHW(16, 15); EPI(); BINIT_ALL(512);
    CHW(17, 0);
    // t6..t9: L2 kt1..12
    WAITB("6"); STAGE3(2, 24); CHW(18, 1);  CHW(19, 2);  CHW(20, 3);
    WAITB("6"); STAGE3(0, 27); CHW(21, 4);  CHW(22, 5);  CHW(23, 6);
    WAITB("6"); STAGE3(1, 30); CHW(24, 7);  CHW(25, 8);  CHW(26, 9);
    WAITB("6"); STAGE3(2, 33); CHW(27, 10); CHW(28, 11); CHW(29, 12);
    // t10: L2 kt13..15
    WAITB("6"); STAGE3(0, 36);
    CHW(30, 13); CHW(31, 14); CHW(32, 15); EPI();
    // t11: L3 (chunks 33,34) + store | net1 L0 (chunk 35)
    WAITB("6"); STAGE3(1, 39);
    {
        f32x16 c3;
        BINIT(c3, 768);
        L3W(33, 0);
        L3W(34, 8);
        if (hi == 0) {
            float* op = out + p * 3;
            op[0] = vis ? c3[0] : 0.0f;
            op[1] = vis ? c3[1] : 0.0f;
            op[2] = vis ? c3[2] : 0.0f;
        }
    }
    L0W(35, 800, xh1); EPI(); BINIT_ALL(800 + 256);

    // ================= net1 =================
    // t12..t16: L1 kt0..14
    WAITB("6"); STAGE3(2, 42); CHW(36, 0);  CHW(37, 1);  CHW(38, 2);
    WAITB("6"); STAGE3(0, 45); CHW(39, 3);  CHW(40, 4);  CHW(41, 5);
    WAITB("6"); STAGE3(1, 48); CHW(42, 6);  CHW(43, 7);  CHW(44, 8);
    WAITB("6"); STAGE3(2, 51); CHW(45, 9);  CHW(46, 10); CHW(47, 11);
    WAITB("6"); STAGE3(0, 54); CHW(48, 12); CHW(49, 13); CHW(50, 14);
    // t17: L1 kt15 | L2 kt0,1
    WAITB("6"); STAGE3(1, 57);
    CHW(51, 15); EPI(); BINIT_ALL(800 + 512);
    CHW(52, 0); CHW(53, 1);
    // t18..t20: L2 kt2..10
    WAITB("6"); STAGE3(2, 60); CHW(54, 2);  CHW(55, 3);  CHW(56, 4);
    WAITB("6"); STAGE3(0, 63); CHW(57, 5);  CHW(58, 6);  CHW(59, 7);
    WAITB("6"); STAGE3(1, 66); CHW(60, 8);  CHW(61, 9);  CHW(62, 10);
    // t21: L2 kt11..13 ; stage last batch (chunk 69, 2 loads)
    WAITB("6"); STAGE_LAST();
    CHW(63, 11); CHW(64, 12); CHW(65, 13);
    // t22: L2 kt14,15 | L3 chunk 68
    WAITB("2");
    {
        CHW(66, 14); CHW(67, 15); EPI();
        f32x16 c3;
        BINIT(c3, 800 + 768);
        L3W(68, 0);
        // t23: L3 chunk 69 + store
        WAITB("0");
        L3W(69, 8);
        if (hi == 0) {
            float* op = out + NPTS * 3 + p * 3;
            op[0] = vis ? c3[0] : 0.0f;
            op[1] = vis ? c3[1] : 0.0f;
            op[2] = vis ? c3[2] : 0.0f;
        }
    }
}

extern "C" void kernel_launch(void* const* d_in, const int* in_sizes, int n_in,
                              void* d_out, int out_size, void* d_ws, size_t ws_size,
                              hipStream_t stream)
{
    f16*   wpk = (f16*)d_ws;
    float* bpk = (float*)((char*)d_ws + BIAS_BYTE);

    prep_kernel<<<147, 256, 0, stream>>>(
        (const float*)d_in[4],  (const float*)d_in[5],
        (const float*)d_in[6],  (const float*)d_in[7],
        (const float*)d_in[8],  (const float*)d_in[9],
        (const float*)d_in[10], (const float*)d_in[11],
        (const float*)d_in[12], (const float*)d_in[13],
        (const float*)d_in[14], (const float*)d_in[15],
        (const float*)d_in[16], (const float*)d_in[17],
        (const float*)d_in[18], (const float*)d_in[19],
        wpk, bpk);

    mlp_kernel<<<2048, 256, 0, stream>>>(
        (const float*)d_in[0], (const float*)d_in[1],
        (const float*)d_in[2], (const float*)d_in[3],
        wpk, bpk, (float*)d_out);
}

// Round 17
// 147.012 us; speedup vs baseline: 2.2381x; 1.0041x over previous
//
#include <hip/hip_runtime.h>

typedef _Float16 f16;
typedef _Float16 f16x8 __attribute__((ext_vector_type(8)));
typedef __fp16   fp16x2 __attribute__((ext_vector_type(2)));
typedef float    f32x16 __attribute__((ext_vector_type(16)));
typedef float    f32x4  __attribute__((ext_vector_type(4)));
typedef unsigned int u32;
typedef unsigned int u32x4 __attribute__((ext_vector_type(4)));

#define NPTS 262144

// ---- packed layout in d_ws (per net, net stride NET_F16 f16) ----
// Weight image = 70 contiguous 8KB chunks (512 x u32x4):
//   net0: L0 (1) | L1 (16) | L2 (16) | L3 (2) = 35 chunks; net1 same.
// Chunk contents: frag[mt][lane][8 f16] (L3: frag[kt][lane][8]).
// A-frag (mfma_f32_32x32x16_f16): A[m][k], m = 32*mt + (lane&31);
//   k(L0) = 8*hi + j canonical (zero-padded); k(L1/L2/L3) PERMUTED:
//   kphys(kt,hi,j) = 32*(kt>>1) + 16*(kt&1) + (j&3) + 8*(j>>2) + 4*hi
//   == C/D layout of previous layer's tile -> zero-shuffle epilogue.
// f32 biases at byte BIAS_BYTE, 800 floats/net, packed in C/D order.
#define NET_F16   143360
#define BIAS_BYTE 573440

static __device__ __forceinline__ u32 pkrtz(float a, float b) {
    fp16x2 h = __builtin_amdgcn_cvt_pkrtz(a, b);
    return __builtin_bit_cast(u32, h);
}
static __device__ __forceinline__ u32 relu_pk(float a, float b) {
    return pkrtz(fmaxf(a, 0.0f), fmaxf(b, 0.0f));
}

// ---------------- weight/bias packing kernel (unchanged, proven) ----------------
__global__ void prep_kernel(
    const float* __restrict__ dW0, const float* __restrict__ db0,
    const float* __restrict__ dW1, const float* __restrict__ db1,
    const float* __restrict__ dW2, const float* __restrict__ db2,
    const float* __restrict__ dW3, const float* __restrict__ db3,
    const float* __restrict__ sW0, const float* __restrict__ sb0,
    const float* __restrict__ sW1, const float* __restrict__ sb1,
    const float* __restrict__ sW2, const float* __restrict__ sb2,
    const float* __restrict__ sW3, const float* __restrict__ sb3,
    f16* __restrict__ wpk, float* __restrict__ bpk)
{
    const int ROWS = 17920;
    int t = blockIdx.x * 256 + threadIdx.x;
    if (t < 2 * ROWS) {
        int net = (t >= ROWS) ? 1 : 0;
        int r = t - net * ROWS;
        const float* W0 = net ? sW0 : dW0;
        const float* W1 = net ? sW1 : dW1;
        const float* W2 = net ? sW2 : dW2;
        const float* W3 = net ? sW3 : dW3;
        int K0 = net ? 8 : 3;
        f16* o = wpk + net * NET_F16;
        if (r < 512) {                                   // L0: canonical slots
            int lane = r & 63;
            int m  = 32 * (r >> 6) + (lane & 31);
            int kb = 8 * (lane >> 5);
            f16* q = o + r * 8;
            #pragma unroll
            for (int j = 0; j < 8; ++j) {
                int k = kb + j;
                q[j] = (f16)((k < K0) ? W0[k * 256 + m] : 0.0f);
            }
        } else if (r < 512 + 8192) {                     // L1: permuted k
            int rr = r - 512;
            int lane = rr & 63;
            int hh = lane >> 5;
            int m  = 32 * ((rr >> 6) & 7) + (lane & 31);
            int kt = rr >> 9;
            f16* q = o + 4096 + rr * 8;
            #pragma unroll
            for (int j = 0; j < 8; ++j) {
                int kp = 32 * (kt >> 1) + 16 * (kt & 1) + (j & 3) + 8 * (j >> 2) + 4 * hh;
                q[j] = (f16)W1[kp * 256 + m];
            }
        } else if (r < 512 + 16384) {                    // L2: permuted k
            int rr = r - (512 + 8192);
            int lane = rr & 63;
            int hh = lane >> 5;
            int m  = 32 * ((rr >> 6) & 7) + (lane & 31);
            int kt = rr >> 9;
            f16* q = o + 69632 + rr * 8;
            #pragma unroll
            for (int j = 0; j < 8; ++j) {
                int kp = 32 * (kt >> 1) + 16 * (kt & 1) + (j & 3) + 8 * (j >> 2) + 4 * hh;
                q[j] = (f16)W2[kp * 256 + m];
            }
        } else {                                         // L3: permuted k
            int rr = r - (512 + 16384);
            int lane = rr & 63;
            int hh = lane >> 5;
            int m  = lane & 31;
            int kt = rr >> 6;
            f16* q = o + 135168 + rr * 8;
            #pragma unroll
            for (int j = 0; j < 8; ++j) {
                int kp = 32 * (kt >> 1) + 16 * (kt & 1) + (j & 3) + 8 * (j >> 2) + 4 * hh;
                q[j] = (f16)((m < 3) ? W3[kp * 3 + m] : 0.0f);
            }
        }
    } else if (t < 2 * ROWS + 1600) {                    // biases (C/D order)
        int tb = t - 2 * ROWS;
        int net = (tb >= 800) ? 1 : 0;
        int i = tb - net * 800;
        float val;
        if (i < 768) {
            int layer = i >> 8;
            const float* bl = net ? (layer == 0 ? sb0 : layer == 1 ? sb1 : sb2)
                                  : (layer == 0 ? db0 : layer == 1 ? db1 : db2);
            int q  = i & 255;
            int rg = q & 15, h = (q >> 4) & 1;
            int m  = 32 * (q >> 5) + (rg & 3) + 8 * (rg >> 2) + 4 * h;
            val = bl[m];
        } else {
            int q  = i - 768;
            int rg = q & 15, h = q >> 4;
            int m  = (rg & 3) + 8 * (rg >> 2) + 4 * h;
            const float* b3 = net ? sb3 : db3;
            val = (m < 3) ? b3[m] : 0.0f;
        }
        bpk[net * 800 + i] = val;
    }
}

// Counted-wait + barrier (T3/T4, R12/R14/R16-proven). setprio(0) first:
// the wave is entering its wait/stage phase (T5 role-split).
#define WAITB(WS) do {                                                          \
    __builtin_amdgcn_s_setprio(0);                                              \
    asm volatile("s_waitcnt vmcnt(" WS ") lgkmcnt(0)" ::: "memory");            \
    __builtin_amdgcn_sched_barrier(0);                                          \
    __builtin_amdgcn_s_barrier();                                               \
    __builtin_amdgcn_sched_barrier(0);                                          \
} while (0)
// Raise priority for the step's compute cluster (after stage-issue).
#define PRIO1() __builtin_amdgcn_s_setprio(1)

// Stage a 3-chunk batch (chunks C0..C0+2, C0 = 3b) into slot S = b%3.
// Wave wv moves rows woff..woff+127 of each chunk: 6 loads/wave/batch.
#define STAGE3(S, C0) do {                                                      \
    _Pragma("unroll")                                                           \
    for (int i_ = 0; i_ < 3; ++i_) {                                            \
        const u32x4* g_ = ws + ((C0) + i_) * 512 + woff + lane;                 \
        u32x4* l_ = &ring[S][i_ * 512 + woff];                                  \
        __builtin_amdgcn_global_load_lds(                                       \
            (const __attribute__((address_space(1))) void*)g_,                  \
            (__attribute__((address_space(3))) void*)l_, 16, 0, 0);             \
        __builtin_amdgcn_global_load_lds(                                       \
            (const __attribute__((address_space(1))) void*)(g_ + 64),           \
            (__attribute__((address_space(3))) void*)(l_ + 64), 16, 0, 0);      \
    }                                                                           \
} while (0)
// Last batch (23) = chunk 69 only -> slot 2, offset 0 (69/3=23, 23%3=2, 69%3=0).
#define STAGE_LAST() do {                                                       \
    const u32x4* g_ = ws + 69 * 512 + woff + lane;                              \
    u32x4* l_ = &ring[2][woff];                                                 \
    __builtin_amdgcn_global_load_lds(                                           \
        (const __attribute__((address_space(1))) void*)g_,                      \
        (__attribute__((address_space(3))) void*)l_, 16, 0, 0);                 \
    __builtin_amdgcn_global_load_lds(                                           \
        (const __attribute__((address_space(1))) void*)(g_ + 64),               \
        (__attribute__((address_space(3))) void*)(l_ + 64), 16, 0, 0);          \
} while (0)

// Chunk C consumed as 256x256 K-tile KT. slot = (C/3)%3, offset = (C%3)*512
// -- all compile-time (C literal). pt=1: 8 ds_read_b128 + 8 MFMA.
#define CHW(C, KT) do {                                                         \
    const u32x4* bq_ = &ring[((C) / 3) % 3][((C) % 3) * 512];                   \
    const f16x8 xh_ = __builtin_bit_cast(f16x8, xf[KT]);                        \
    _Pragma("unroll")                                                           \
    for (int mt_ = 0; mt_ < 8; ++mt_) {                                         \
        const f16x8 a_ = __builtin_bit_cast(f16x8, bq_[mt_ * 64 + lane]);       \
        acc[mt_] = __builtin_amdgcn_mfma_f32_32x32x16_f16(a_, xh_, acc[mt_], 0, 0, 0); \
    }                                                                           \
} while (0)

// L3 chunk C with xf base HB into c3.
#define L3W(C, HB) do {                                                         \
    const u32x4* bq_ = &ring[((C) / 3) % 3][((C) % 3) * 512];                   \
    _Pragma("unroll")                                                           \
    for (int i_ = 0; i_ < 8; ++i_) {                                            \
        const f16x8 a_ = __builtin_bit_cast(f16x8, bq_[i_ * 64 + lane]);        \
        c3 = __builtin_amdgcn_mfma_f32_32x32x16_f16(                            \
                a_, __builtin_bit_cast(f16x8, xf[(HB) + i_]), c3, 0, 0, 0);     \
    }                                                                           \
} while (0)

// L0 of a net from chunk C (bias-init per-mt, canonical input frag XH).
#define L0W(C, BB, XH) do {                                                     \
    const u32x4* bq_ = &ring[((C) / 3) % 3][((C) % 3) * 512];                   \
    _Pragma("unroll")                                                           \
    for (int mt_ = 0; mt_ < 8; ++mt_) {                                         \
        f32x16 ci_;                                                             \
        BINIT(ci_, (BB) + mt_ * 32);                                            \
        const f16x8 a_ = __builtin_bit_cast(f16x8, bq_[mt_ * 64 + lane]);       \
        acc[mt_] = __builtin_amdgcn_mfma_f32_32x32x16_f16(a_, XH, ci_, 0, 0, 0);\
    }                                                                           \
} while (0)

#define BINIT(dst, boff) do {                                                   \
    const f32x4* b4_ = (const f32x4*)(biasl + (boff) + hi * 16);                \
    const f32x4 v0_ = b4_[0], v1_ = b4_[1], v2_ = b4_[2], v3_ = b4_[3];         \
    _Pragma("unroll")                                                           \
    for (int j = 0; j < 4; ++j) {                                               \
        (dst)[j] = v0_[j]; (dst)[4 + j] = v1_[j];                               \
        (dst)[8 + j] = v2_[j]; (dst)[12 + j] = v3_[j];                          \
    }                                                                           \
} while (0)

#define BINIT_ALL(boff) do {                                                    \
    _Pragma("unroll")                                                           \
    for (int mt = 0; mt < 8; ++mt) BINIT(acc[mt], (boff) + mt * 32);            \
} while (0)

// Zero-shuffle epilogue (static indices only, rule #20).
#define EPI() do {                                                              \
    _Pragma("unroll")                                                           \
    for (int mt = 0; mt < 8; ++mt) {                                            \
        _Pragma("unroll")                                                       \
        for (int q = 0; q < 2; ++q) {                                           \
            u32x4 w;                                                            \
            w[0] = relu_pk(acc[mt][8*q+0], acc[mt][8*q+1]);                     \
            w[1] = relu_pk(acc[mt][8*q+2], acc[mt][8*q+3]);                     \
            w[2] = relu_pk(acc[mt][8*q+4], acc[mt][8*q+5]);                     \
            w[3] = relu_pk(acc[mt][8*q+6], acc[mt][8*q+7]);                     \
            xf[2*mt+q] = w;                                                     \
        }                                                                       \
    }                                                                           \
} while (0)

// ---------------- fused dual-MLP kernel ----------------
// 256 thr = 4 waves, 32 points/wave (pt=1), grid 2048, 2 blocks/CU,
// 2 waves/SIMD. 3-chunk batches in a 3-slot ring (72KB), depth-2
// counted-vmcnt, 24 barrier-steps. NEW vs R16: T5 setprio role-split —
// priority 1 inside each step's compute cluster, 0 during wait/stage.
__launch_bounds__(256, 2)
__global__ void mlp_kernel(const float* __restrict__ gn, const float* __restrict__ gv,
                           const float* __restrict__ gro, const float* __restrict__ gr0,
                           const f16* __restrict__ wpk, const float* __restrict__ bpk,
                           float* __restrict__ out)
{
    __shared__ u32x4 ring[3][1536];                // 3 x 24KB slots = 72KB
    __shared__ __align__(16) float biasl[1600];    // 6.4KB biases

    const int tid  = threadIdx.x;
    const int wv   = tid >> 6;
    const int lane = tid & 63;
    const int l32  = lane & 31;
    const int hi   = lane >> 5;
    const int p    = blockIdx.x * 128 + wv * 32 + l32;
    const int woff = wv * 128;
    const u32x4* ws = (const u32x4*)wpk;           // 70-chunk contiguous stream

    // ---- biases -> LDS ----
    biasl[tid]        = bpk[tid];
    biasl[tid + 256]  = bpk[tid + 256];
    biasl[tid + 512]  = bpk[tid + 512];
    biasl[tid + 768]  = bpk[tid + 768];
    biasl[tid + 1024] = bpk[tid + 1024];
    biasl[tid + 1280] = bpk[tid + 1280];
    if (tid < 64) biasl[tid + 1536] = bpk[tid + 1536];

    // ---- inputs (before the pipeline: keeps the vmcnt window pure) ----
    u32x4 xd = {0,0,0,0}, xs = {0,0,0,0};
    bool vis = false;
    if (hi == 0) {               // hi lanes hold k=8..15 (zero-padded)
        float nx = gn[3*p], ny = gn[3*p+1], nz = gn[3*p+2];
        float vx = gv[3*p], vy = gv[3*p+1], vz = gv[3*p+2];
        float ro = gro[p], rr = gr0[p];
        float ni = 1.0f / fmaxf(sqrtf(nx*nx + ny*ny + nz*nz), 1e-12f);
        float vi = 1.0f / fmaxf(sqrtf(vx*vx + vy*vy + vz*vz), 1e-12f);
        nx *= ni; ny *= ni; nz *= ni; vx *= vi; vy *= vi; vz *= vi;
        vis = (nx*vx + ny*vy + nz*vz) > 0.0f;
        xd[0] = pkrtz(nx, ny); xd[1] = pkrtz(nz, 0.0f);
        xs[0] = xd[0];         xs[1] = pkrtz(nz, vx);
        xs[2] = pkrtz(vy, vz); xs[3] = pkrtz(ro, rr);
    }

    // drain input/bias traffic, publish biasl (single full sync, pre-pipeline)
    __syncthreads();

    // ---- prologue: batches 0 (chunks 0-2 -> slot 0) and 1 (3-5 -> slot 1) ----
    STAGE3(0, 0);
    STAGE3(1, 3);

    f32x16 acc[8];    // 128 regs -> AGPRs
    u32x4  xf[16];    // 64 VGPRs
    const f16x8 xh0 = __builtin_bit_cast(f16x8, xd);
    const f16x8 xh1 = __builtin_bit_cast(f16x8, xs);

    // ================= net0 =================
    // t0: L0 + L1 kt0,1
    WAITB("6"); STAGE3(2, 6); PRIO1();
    L0W(0, 0, xh0); EPI(); BINIT_ALL(256);
    CHW(1, 0); CHW(2, 1);
    // t1..t4: L1 kt2..13
    WAITB("6"); STAGE3(0, 9);  PRIO1(); CHW(3, 2);  CHW(4, 3);  CHW(5, 4);
    WAITB("6"); STAGE3(1, 12); PRIO1(); CHW(6, 5);  CHW(7, 6);  CHW(8, 7);
    WAITB("6"); STAGE3(2, 15); PRIO1(); CHW(9, 8);  CHW(10, 9); CHW(11, 10);
    WAITB("6"); STAGE3(0, 18); PRIO1(); CHW(12, 11); CHW(13, 12); CHW(14, 13);
    // t5: L1 kt14,15 | L2 kt0
    WAITB("6"); STAGE3(1, 21); PRIO1();
    CHW(15, 14); CHW(16, 15); EPI(); BINIT_ALL(512);
    CHW(17, 0);
    // t6..t9: L2 kt1..12
    WAITB("6"); STAGE3(2, 24); PRIO1(); CHW(18, 1);  CHW(19, 2);  CHW(20, 3);
    WAITB("6"); STAGE3(0, 27); PRIO1(); CHW(21, 4);  CHW(22, 5);  CHW(23, 6);
    WAITB("6"); STAGE3(1, 30); PRIO1(); CHW(24, 7);  CHW(25, 8);  CHW(26, 9);
    WAITB("6"); STAGE3(2, 33); PRIO1(); CHW(27, 10); CHW(28, 11); CHW(29, 12);
    // t10: L2 kt13..15
    WAITB("6"); STAGE3(0, 36); PRIO1();
    CHW(30, 13); CHW(31, 14); CHW(32, 15); EPI();
    // t11: L3 (chunks 33,34) + store | net1 L0 (chunk 35)
    WAITB("6"); STAGE3(1, 39); PRIO1();
    {
        f32x16 c3;
        BINIT(c3, 768);
        L3W(33, 0);
        L3W(34, 8);
        if (hi == 0) {
            float* op = out + p * 3;
            op[0] = vis ? c3[0] : 0.0f;
            op[1] = vis ? c3[1] : 0.0f;
            op[2] = vis ? c3[2] : 0.0f;
        }
    }
    L0W(35, 800, xh1); EPI(); BINIT_ALL(800 + 256);

    // ================= net1 =================
    // t12..t16: L1 kt0..14
    WAITB("6"); STAGE3(2, 42); PRIO1(); CHW(36, 0);  CHW(37, 1);  CHW(38, 2);
    WAITB("6"); STAGE3(0, 45); PRIO1(); CHW(39, 3);  CHW(40, 4);  CHW(41, 5);
    WAITB("6"); STAGE3(1, 48); PRIO1(); CHW(42, 6);  CHW(43, 7);  CHW(44, 8);
    WAITB("6"); STAGE3(2, 51); PRIO1(); CHW(45, 9);  CHW(46, 10); CHW(47, 11);
    WAITB("6"); STAGE3(0, 54); PRIO1(); CHW(48, 12); CHW(49, 13); CHW(50, 14);
    // t17: L1 kt15 | L2 kt0,1
    WAITB("6"); STAGE3(1, 57); PRIO1();
    CHW(51, 15); EPI(); BINIT_ALL(800 + 512);
    CHW(52, 0); CHW(53, 1);
    // t18..t20: L2 kt2..10
    WAITB("6"); STAGE3(2, 60); PRIO1(); CHW(54, 2);  CHW(55, 3);  CHW(56, 4);
    WAITB("6"); STAGE3(0, 63); PRIO1(); CHW(57, 5);  CHW(58, 6);  CHW(59, 7);
    WAITB("6"); STAGE3(1, 66); PRIO1(); CHW(60, 8);  CHW(61, 9);  CHW(62, 10);
    // t21: L2 kt11..13 ; stage last batch (chunk 69, 2 loads)
    WAITB("6"); STAGE_LAST(); PRIO1();
    CHW(63, 11); CHW(64, 12); CHW(65, 13);
    // t22: L2 kt14,15 | L3 chunk 68
    WAITB("2"); PRIO1();
    {
        CHW(66, 14); CHW(67, 15); EPI();
        f32x16 c3;
        BINIT(c3, 800 + 768);
        L3W(68, 0);
        // t23: L3 chunk 69 + store
        WAITB("0"); PRIO1();
        L3W(69, 8);
        __builtin_amdgcn_s_setprio(0);
        if (hi == 0) {
            float* op = out + NPTS * 3 + p * 3;
            op[0] = vis ? c3[0] : 0.0f;
            op[1] = vis ? c3[1] : 0.0f;
            op[2] = vis ? c3[2] : 0.0f;
        }
    }
}

extern "C" void kernel_launch(void* const* d_in, const int* in_sizes, int n_in,
                              void* d_out, int out_size, void* d_ws, size_t ws_size,
                              hipStream_t stream)
{
    f16*   wpk = (f16*)d_ws;
    float* bpk = (float*)((char*)d_ws + BIAS_BYTE);

    prep_kernel<<<147, 256, 0, stream>>>(
        (const float*)d_in[4],  (const float*)d_in[5],
        (const float*)d_in[6],  (const float*)d_in[7],
        (const float*)d_in[8],  (const float*)d_in[9],
        (const float*)d_in[10], (const float*)d_in[11],
        (const float*)d_in[12], (const float*)d_in[13],
        (const float*)d_in[14], (const float*)d_in[15],
        (const float*)d_in[16], (const float*)d_in[17],
        (const float*)d_in[18], (const float*)d_in[19],
        wpk, bpk);

    mlp_kernel<<<2048, 256, 0, stream>>>(
        (const float*)d_in[0], (const float*)d_in[1],
        (const float*)d_in[2], (const float*)d_in[3],
        wpk, bpk, (float*)d_out);
}